// Round 5
// baseline (149.526 us; speedup 1.0000x reference)
//
#include <hip/hip_runtime.h>
#include <math.h>

#define IN_F   1024
#define OUT_F  1024
#define TASK_D 256
#define RANK   8
#define HID    64
// SCALING = ALPHA / RANK = 1.0 (identity)

__device__ __forceinline__ float gelu_exact(float v) {
    return 0.5f * v * (1.0f + erff(v * 0.70710678118654752f));
}

// ---------------------------------------------------------------------------
// Kernel 1: generate LoRA tables for all 4 tasks (unchanged — verified).
//   vec_a_t : [4][RANK][OUT_F]  (TRANSPOSED: a_t[t][r][o] = a[t][o][r])
//   vec_b   : [4][RANK][IN_F]   (natural Wb2 row order)
// ---------------------------------------------------------------------------
__global__ __launch_bounds__(256) void gen_kernel(
    const float* __restrict__ task_emb,
    const float* __restrict__ Wa1, const float* __restrict__ ba1,
    const float* __restrict__ Wa2, const float* __restrict__ ba2,
    const float* __restrict__ Wb1, const float* __restrict__ bb1,
    const float* __restrict__ Wb2, const float* __restrict__ bb2,
    float* __restrict__ vec_a_t, float* __restrict__ vec_b)
{
    const int gen = blockIdx.x >> 7;             // 0 -> a, 1 -> b
    const int blk = blockIdx.x & 127;
    const float* __restrict__ W1 = gen ? Wb1 : Wa1;
    const float* __restrict__ b1 = gen ? bb1 : ba1;
    const float* __restrict__ W2 = gen ? Wb2 : Wa2;
    const float* __restrict__ b2 = gen ? bb2 : ba2;

    __shared__ float hs[4][HID];
    {
        const int j = threadIdx.x >> 2;          // hidden unit 0..63
        const int t = threadIdx.x & 3;           // task 0..3
        const float4* te = (const float4*)(task_emb + t * TASK_D);
        const float4* w  = (const float4*)(W1 + j * TASK_D);
        float acc = 0.f;
        #pragma unroll
        for (int d = 0; d < TASK_D / 4; ++d) {
            float4 a = te[d], b = w[d];
            acc += a.x * b.x + a.y * b.y + a.z * b.z + a.w * b.w;
        }
        hs[t][j] = gelu_exact(acc + b1[j]);
    }
    __syncthreads();

    const int lrow = threadIdx.x >> 2;           // 0..63  (W2 row within block)
    const int q    = threadIdx.x & 3;            // quarter of the 64 hidden dims
    const int o    = blk * 64 + lrow;            // W2 row 0..8191

    const float4* w2 = (const float4*)(W2 + (size_t)o * HID + q * 16);
    float acc0 = 0.f, acc1 = 0.f, acc2 = 0.f, acc3 = 0.f;
    #pragma unroll
    for (int k = 0; k < 4; ++k) {
        float4 w = w2[k];
        const int kb = q * 16 + k * 4;
        acc0 += hs[0][kb] * w.x + hs[0][kb+1] * w.y + hs[0][kb+2] * w.z + hs[0][kb+3] * w.w;
        acc1 += hs[1][kb] * w.x + hs[1][kb+1] * w.y + hs[1][kb+2] * w.z + hs[1][kb+3] * w.w;
        acc2 += hs[2][kb] * w.x + hs[2][kb+1] * w.y + hs[2][kb+2] * w.z + hs[2][kb+3] * w.w;
        acc3 += hs[3][kb] * w.x + hs[3][kb+1] * w.y + hs[3][kb+2] * w.z + hs[3][kb+3] * w.w;
    }
    #pragma unroll
    for (int off = 1; off <= 2; off <<= 1) {
        acc0 += __shfl_xor(acc0, off, 64);
        acc1 += __shfl_xor(acc1, off, 64);
        acc2 += __shfl_xor(acc2, off, 64);
        acc3 += __shfl_xor(acc3, off, 64);
    }
    if (q == 0) {
        const float bb = b2[o];
        float v[4] = { acc0 + bb, acc1 + bb, acc2 + bb, acc3 + bb };
        if (gen == 0) {
            const int oo = o >> 3, r = o & 7;    // vec_a row o -> (out oo, rank r)
            #pragma unroll
            for (int t = 0; t < 4; ++t)
                vec_a_t[t * (RANK * OUT_F) + r * OUT_F + oo] = v[t];
        } else {
            #pragma unroll
            for (int t = 0; t < 4; ++t)
                vec_b[t * (RANK * IN_F) + o] = v[t];
        }
    }
}

// ---------------------------------------------------------------------------
// Kernel 2 (v5): tmp[row][r] = x[row] . b[t][r].
// One row per 64-lane wave; 2048 blocks x 4 waves = 8192 waves = 32/CU.
// Blocks task-contiguous so a CU's L1 holds exactly ONE 32 KB b-table
// (exact L1 fit -> table reads are L1 hits). Bound by the 32 MB x read.
// Butterfly-reduces across 64 lanes; lane 0 writes 32 B of tmp.
// ---------------------------------------------------------------------------
__global__ __launch_bounds__(256) void tmp_kernel(
    const float* __restrict__ x, const float* __restrict__ vec_b,
    float* __restrict__ tmp, int waves_per_task)
{
    const int wave = threadIdx.x >> 6;
    const int ln   = threadIdx.x & 63;
    const int gw   = blockIdx.x * 4 + wave;      // global wave id
    const int t    = gw / waves_per_task;        // task 0..3
    const int j    = gw % waves_per_task;        // within-task row index
    const int row  = t + 4 * j;                  // global row

    const float* __restrict__ xr = x + (size_t)row * IN_F;
    const float* __restrict__ bt = vec_b + (size_t)t * (RANK * IN_F);

    float4 xv[4];
    #pragma unroll
    for (int c = 0; c < 4; ++c)
        xv[c] = *(const float4*)(xr + c * 256 + ln * 4);

    float acc[RANK];
    #pragma unroll
    for (int r = 0; r < RANK; ++r) acc[r] = 0.f;

    #pragma unroll
    for (int c = 0; c < 4; ++c) {
        const int k = c * 256 + ln * 4;
        #pragma unroll
        for (int r = 0; r < RANK; ++r) {
            const float4 bv = *(const float4*)(bt + r * IN_F + k);
            acc[r] += xv[c].x * bv.x + xv[c].y * bv.y + xv[c].z * bv.z + xv[c].w * bv.w;
        }
    }

    #pragma unroll
    for (int off = 1; off <= 32; off <<= 1) {
        #pragma unroll
        for (int r = 0; r < RANK; ++r)
            acc[r] += __shfl_xor(acc[r], off, 64);
    }

    if (ln == 0) {
        float* __restrict__ tr = tmp + (size_t)row * RANK;
        *(float4*)(tr)     = make_float4(acc[0], acc[1], acc[2], acc[3]);
        *(float4*)(tr + 4) = make_float4(acc[4], acc[5], acc[6], acc[7]);
    }
}

// ---------------------------------------------------------------------------
// Kernel 3 (v5): out[row][o] = base_out[row][o] + sum_r tmp[row][r]*a_t[t][r][o].
// Pure streaming triad, NO cross-lane ops. Thread tid owns column o=tid*4
// for the whole block; holds its 8 a-fragments in 32 VGPRs (a-table alone
// in L1). 4 rows per block, all base/tmp loads hoisted (4 HBM loads in
// flight/thread). 2048 blocks, task-contiguous. Bound by base+out 64 MB.
// ---------------------------------------------------------------------------
__global__ __launch_bounds__(256, 4) void out_kernel(
    const float* __restrict__ base_out, const float* __restrict__ vec_a_t,
    const float* __restrict__ tmp, float* __restrict__ out,
    int blocks_per_task)
{
    const int t = blockIdx.x / blocks_per_task;  // task 0..3
    const int g = blockIdx.x % blocks_per_task;  // group within task
    const int o = threadIdx.x * 4;               // column (block covers 1024)

    const float* __restrict__ at = vec_a_t + (size_t)t * (RANK * OUT_F);
    float4 af[RANK];
    #pragma unroll
    for (int r = 0; r < RANK; ++r)
        af[r] = *(const float4*)(at + r * OUT_F + o);

    int   row[4];
    float4 bo[4], t0[4], t1[4];
    #pragma unroll
    for (int i = 0; i < 4; ++i) {
        row[i] = t + 4 * (g * 4 + i);
        bo[i] = *(const float4*)(base_out + (size_t)row[i] * OUT_F + o);
        const float* __restrict__ tr = tmp + (size_t)row[i] * RANK;
        t0[i] = *(const float4*)(tr);
        t1[i] = *(const float4*)(tr + 4);
    }

    #pragma unroll
    for (int i = 0; i < 4; ++i) {
        const float s[RANK] = { t0[i].x, t0[i].y, t0[i].z, t0[i].w,
                                t1[i].x, t1[i].y, t1[i].z, t1[i].w };
        float4 rv = bo[i];
        #pragma unroll
        for (int r = 0; r < RANK; ++r) {
            rv.x += s[r] * af[r].x;
            rv.y += s[r] * af[r].y;
            rv.z += s[r] * af[r].z;
            rv.w += s[r] * af[r].w;
        }
        *(float4*)(out + (size_t)row[i] * OUT_F + o) = rv;
    }
}

extern "C" void kernel_launch(void* const* d_in, const int* in_sizes, int n_in,
                              void* d_out, int out_size, void* d_ws, size_t ws_size,
                              hipStream_t stream) {
    const float* x        = (const float*)d_in[0];
    const float* base_out = (const float*)d_in[1];
    const float* task_emb = (const float*)d_in[2];
    const float* Wa1      = (const float*)d_in[3];
    const float* ba1      = (const float*)d_in[4];
    const float* Wa2      = (const float*)d_in[5];
    const float* ba2      = (const float*)d_in[6];
    const float* Wb1      = (const float*)d_in[7];
    const float* bb1      = (const float*)d_in[8];
    const float* Wb2      = (const float*)d_in[9];
    const float* bb2      = (const float*)d_in[10];
    float* out = (float*)d_out;

    float* vec_a_t = (float*)d_ws;                        // 4*8192 floats
    float* vec_b   = vec_a_t + 4 * RANK * OUT_F;          // 4*8192 floats
    float* tmp     = vec_b   + 4 * RANK * IN_F;           // 8192*8 floats

    const int b_eff = in_sizes[0] / IN_F;                 // 8192

    gen_kernel<<<256, 256, 0, stream>>>(task_emb, Wa1, ba1, Wa2, ba2,
                                        Wb1, bb1, Wb2, bb2, vec_a_t, vec_b);

    // K2: one row per wave, 4 waves/block.
    const int nblk2 = b_eff / 4;                          // 2048 blocks
    tmp_kernel<<<nblk2, 256, 0, stream>>>(x, vec_b, tmp, b_eff / 4);

    // K3: 4 rows per block, thread = one column slice.
    const int nblk3 = b_eff / 4;                          // 2048 blocks
    out_kernel<<<nblk3, 256, 0, stream>>>(base_out, vec_a_t, tmp, out,
                                          nblk3 / 4);
}